// Round 5
// baseline (3664.564 us; speedup 1.0000x reference)
//
#include <hip/hip_runtime.h>
#include <hip/hip_bf16.h>

#define VOCAB 4096
#define BB 4
#define LL 2048
#define SEG 16
#define SEGL 128  // LL/SEG

typedef __hip_bfloat16 bf16;
typedef __bf16 bf16x8 __attribute__((ext_vector_type(8)));
typedef float f32x4 __attribute__((ext_vector_type(4)));

__device__ __forceinline__ void gload16(const void* g, void* l) {
  __builtin_amdgcn_global_load_lds(
      (const __attribute__((address_space(1))) unsigned int*)g,
      (__attribute__((address_space(3))) unsigned int*)l, 16, 0, 0);
}

// ---------------- transpose f32 [K][N] -> bf16 [N][K] ----------------
__global__ void transpose_f32_bf16(const float* __restrict__ in,
                                   bf16* __restrict__ out, int K, int N) {
  __shared__ float tile[32][33];
  int bx = blockIdx.x;  // tile along N
  int by = blockIdx.y;  // tile along K
  int x = bx * 32 + threadIdx.x;
#pragma unroll
  for (int i = threadIdx.y; i < 32; i += 8)
    tile[i][threadIdx.x] = in[(size_t)(by * 32 + i) * N + x];
  __syncthreads();
  int k = by * 32 + threadIdx.x;
#pragma unroll
  for (int i = threadIdx.y; i < 32; i += 8)
    out[(size_t)(bx * 32 + i) * K + k] = __float2bfloat16(tile[threadIdx.x][i]);
}

// -------- ctx pass A: per-segment sigmoid column sums --------
__global__ void ctx_partial(const int* __restrict__ idx,
                            const float* __restrict__ Mlog,
                            float* __restrict__ segsum) {
  int b = blockIdx.x / (16 * SEG);
  int rem = blockIdx.x % (16 * SEG);
  int chunk = rem / SEG;
  int s = rem % SEG;
  int col = chunk * 256 + threadIdx.x;
  __shared__ int sidx[SEGL];
  if (threadIdx.x < SEGL)
    sidx[threadIdx.x] = idx[b * LL + s * SEGL + threadIdx.x];
  __syncthreads();
  const float* base = Mlog + col;
  float a0 = 0.f, a1 = 0.f, a2 = 0.f, a3 = 0.f;
#pragma unroll 4
  for (int t = 0; t < SEGL; t += 4) {
    float v0 = base[(size_t)sidx[t + 0] * VOCAB];
    float v1 = base[(size_t)sidx[t + 1] * VOCAB];
    float v2 = base[(size_t)sidx[t + 2] * VOCAB];
    float v3 = base[(size_t)sidx[t + 3] * VOCAB];
    a0 += 1.f / (1.f + __expf(-v0));
    a1 += 1.f / (1.f + __expf(-v1));
    a2 += 1.f / (1.f + __expf(-v2));
    a3 += 1.f / (1.f + __expf(-v3));
  }
  segsum[(size_t)blockIdx.x * 256 + threadIdx.x] = (a0 + a1) + (a2 + a3);
}

// -------- ctx pass B: replay segment with offset, write running mean --------
__global__ void ctx_final(const int* __restrict__ idx,
                          const float* __restrict__ Mlog,
                          const float* __restrict__ segsum,
                          bf16* __restrict__ ctx) {
  int b = blockIdx.x / (16 * SEG);
  int rem = blockIdx.x % (16 * SEG);
  int chunk = rem / SEG;
  int s = rem % SEG;
  int col = chunk * 256 + threadIdx.x;
  __shared__ int sidx[SEGL];
  if (threadIdx.x < SEGL)
    sidx[threadIdx.x] = idx[b * LL + s * SEGL + threadIdx.x];
  __syncthreads();
  const float* ss = segsum + (size_t)((b * 16 + chunk) * SEG) * 256 + threadIdx.x;
  float acc = 0.f;
  for (int s2 = 0; s2 < s; ++s2) acc += ss[(size_t)s2 * 256];
  const float* base = Mlog + col;
  bf16* outp = ctx + ((size_t)b * LL + (size_t)s * SEGL) * VOCAB + col;
#pragma unroll 8
  for (int t = 0; t < SEGL; ++t) {
    float v = base[(size_t)sidx[t] * VOCAB];
    acc += 1.f / (1.f + __expf(-v));
    float inv = __fdividef(1.f, (float)(s * SEGL + t + 1));
    outp[(size_t)t * VOCAB] = __float2bfloat16(acc * inv);
  }
}

// ---------------- 256x256 bf16 GEMM, 1-phase read-skew schedule ----------
// C = A[M][K] * Bt[N][K]^T + bias. 512 thr (2x4 waves), BK=64, 128KiB LDS
// dbuf, chunk-XOR swizzle (0 conflicts). ds_reads issued one phase AHEAD of
// their MFMA (counted lgkm), stages 2 phases ahead of reads (counted vmcnt).
// Quadrant order (0,0),(0,1),(1,1),(1,0); A0 held full tile, B0 parity-dbuf.
// launch_bounds(512,1): LDS already caps at 1 block/CU; give the allocator
// the full 256-VGPR + AGPR budget so the ~112 live fragment regs don't spill
// (round-4 lesson: (512,2) capped VGPR at 128 -> 1.7GB scratch traffic).
// EPI==0: out = bf16 gelu_exact(C)   EPI==1: out = f32 C

#define BAR() asm volatile("s_barrier" ::: "memory")
#define LGKM(n_) asm volatile("s_waitcnt lgkmcnt(" #n_ ")" ::: "memory")
#define VMW(n_) asm volatile("s_waitcnt vmcnt(" #n_ ")" ::: "memory")
#define SB0() __builtin_amdgcn_sched_barrier(0)
#define P1() __builtin_amdgcn_s_setprio(1)
#define P0() __builtin_amdgcn_s_setprio(0)

// stage one half-tile (128 rows x 64 cols) of A or B into buffer b
#define STG_A(t_, h_, b_)                                           \
  {                                                                 \
    const bf16* s_ = Asrc + (size_t)(h_)*128 * K + (size_t)(t_)*64; \
    bf16* d_ = sm + (b_)*32768 + (h_)*8192 + wave * 512;            \
    gload16(s_, d_);                                                \
    gload16(s_ + rowK64, d_ + 4096);                                \
  }
#define STG_B(t_, h_, b_)                                           \
  {                                                                 \
    const bf16* s_ = Bsrc + (size_t)(h_)*128 * K + (size_t)(t_)*64; \
    bf16* d_ = sm + (b_)*32768 + 16384 + (h_)*8192 + wave * 512;    \
    gload16(s_, d_);                                                \
    gload16(s_ + 4096ull * 0 + rowK64, d_ + 4096);                  \
  }

// fragment load: slot = row*8 + (kc ^ (row&7)); row&7 == rsel&7 == xorv
#define LDF(base_, row_, kc_) \
  (*(const bf16x8*)((base_) + (row_)*64 + ((((kc_) ^ xorv)) << 3)))

#define RD_A(dst_, base_, mh_)                       \
  _Pragma("unroll") for (int i_ = 0; i_ < 4; ++i_) { \
    int row_ = (mh_)*128 + wm64 + i_ * 16 + rsel;    \
    dst_[i_][0] = LDF(base_, row_, ksel);            \
    dst_[i_][1] = LDF(base_, row_, 4 + ksel);        \
  }
#define RD_B(dst_, base_, nh_)                       \
  _Pragma("unroll") for (int j_ = 0; j_ < 2; ++j_) { \
    int row_ = (nh_)*128 + wn32 + j_ * 16 + rsel;    \
    dst_[j_][0] = LDF(base_, row_, ksel);            \
    dst_[j_][1] = LDF(base_, row_, 4 + ksel);        \
  }

#define MQ(mh_, nh_, A_, B_)                                              \
  _Pragma("unroll") for (int i_ = 0; i_ < 4; ++i_)                        \
      _Pragma("unroll") for (int j_ = 0; j_ < 2; ++j_) {                  \
    f32x4& c_ = acc[(mh_)*4 + i_][(nh_)*2 + j_];                          \
    c_ = __builtin_amdgcn_mfma_f32_16x16x32_bf16(A_[i_][0], B_[j_][0],    \
                                                 c_, 0, 0, 0);            \
    c_ = __builtin_amdgcn_mfma_f32_16x16x32_bf16(A_[i_][1], B_[j_][1],    \
                                                 c_, 0, 0, 0);            \
  }

// One K-tile. T_: tile index (compile-known parity), bc_: buffer (literal),
// b0c_: B0 regs for THIS tile, b0n_: B0 regs to fill for tile T_+1.
#define TILE_BODY(T_, bc_, b0c_, b0n_)                              \
  {                                                                 \
    const bf16* Ab = sm + (bc_)*32768;                              \
    const bf16* Bb = Ab + 16384;                                    \
    const bf16* Abn = sm + ((bc_) ^ 1) * 32768;                     \
    const bf16* Bbn = Abn + 16384;                                  \
    /* ph1: rd b1f (for ph2); stg A0'; MFMA (0,0) = a0f x b0c */    \
    VMW(2);                                                         \
    BAR();                                                          \
    RD_B(b1f, Bb, 1);                                               \
    if ((T_) + 1 < NT) STG_A((T_) + 1, 0, (bc_) ^ 1);               \
    BAR();                                                          \
    LGKM(4);                                                        \
    SB0();                                                          \
    P1();                                                           \
    MQ(0, 0, a0f, b0c_);                                            \
    P0();                                                           \
    /* ph2: rd a1f (for ph3); stg B0'; MFMA (0,1) = a0f x b1f */    \
    if ((T_) + 1 < NT) { VMW(2); } else { VMW(0); }                 \
    BAR();                                                          \
    RD_A(a1f, Ab, 1);                                               \
    if ((T_) + 1 < NT) STG_B((T_) + 1, 0, (bc_) ^ 1);               \
    BAR();                                                          \
    LGKM(8);                                                        \
    SB0();                                                          \
    P1();                                                           \
    MQ(0, 1, a0f, b1f);                                             \
    P0();                                                           \
    /* ph3: no reads; stg B1'; MFMA (1,1) = a1f x b1f */            \
    if ((T_) + 1 < NT) STG_B((T_) + 1, 1, (bc_) ^ 1);               \
    BAR();                                                          \
    LGKM(0);                                                        \
    SB0();                                                          \
    P1();                                                           \
    MQ(1, 1, a1f, b1f);                                             \
    P0();                                                           \
    /* ph4: rd a0f,b0n <- tile T_+1 (bnx); stg A1'; MFMA (1,0) */   \
    VMW(2);                                                         \
    BAR();                                                          \
    if ((T_) + 1 < NT) {                                            \
      RD_A(a0f, Abn, 0);                                            \
      RD_B(b0n_, Bbn, 0);                                           \
    }                                                               \
    if ((T_) + 1 < NT) STG_A((T_) + 1, 1, (bc_) ^ 1);               \
    BAR();                                                          \
    LGKM(12);                                                       \
    SB0();                                                          \
    P1();                                                           \
    MQ(1, 0, a1f, b0c_);                                            \
    P0();                                                           \
  }

template <int EPI>
__global__ __launch_bounds__(512, 1) void gemm256(const bf16* __restrict__ A,
                                                  const bf16* __restrict__ Bt,
                                                  const float* __restrict__ bias,
                                                  void* __restrict__ outv,
                                                  int M, int N, int K) {
  __shared__ __align__(16) bf16 sm[65536];  // 128 KiB: 2 x (A 32KB | B 32KB)
  const int tid = threadIdx.x;
  const int wave = tid >> 6;
  const int lane = tid & 63;
  const int nwg = gridDim.x;
  const int bid = blockIdx.x;
  const int swz = (bid & 7) * (nwg >> 3) + (bid >> 3);  // nwg % 8 == 0
  const int gn = N >> 8;
  const int bm0 = (swz / gn) << 8;
  const int bn0 = (swz % gn) << 8;
  const int wm64 = (wave >> 2) << 6;  // wave_m * 64
  const int wn32 = (wave & 3) << 5;   // wave_n * 32
  const int rsel = lane & 15;
  const int ksel = lane >> 4;
  const int xorv = rsel & 7;

  // staging source: thread covers slots tid and tid+512 of each half-tile;
  // slot p -> row=p>>3, kc=(p&7)^(row&7)
  const int r0 = tid >> 3;
  const int kc0 = (tid & 7) ^ (r0 & 7);
  const bf16* Asrc = A + (size_t)(bm0 + r0) * K + kc0 * 8;
  const bf16* Bsrc = Bt + (size_t)(bn0 + r0) * K + kc0 * 8;
  const size_t rowK64 = (size_t)64 * K;
  const int NT = K >> 6;

  f32x4 acc[8][4];
#pragma unroll
  for (int i = 0; i < 8; ++i)
#pragma unroll
    for (int j = 0; j < 4; ++j) acc[i][j] = (f32x4){0.f, 0.f, 0.f, 0.f};

  bf16x8 a0f[4][2], a1f[4][2], b0fE[2][2], b0fO[2][2], b1f[2][2];

  // prologue: stage tile0 {A0,B0,B1,A1} -> buf0 (order = read order)
  STG_A(0, 0, 0);
  STG_B(0, 0, 0);
  STG_B(0, 1, 0);
  STG_A(0, 1, 0);
  VMW(4);  // A0,B0 landed; B1,A1 still in flight
  BAR();
  RD_A(a0f, sm, 0);
  RD_B(b0fE, sm + 16384, 0);

  for (int t = 0; t < NT; t += 2) {
    TILE_BODY(t, 0, b0fE, b0fO);
    TILE_BODY(t + 1, 1, b0fO, b0fE);
  }

  // epilogue; C/D layout: col = lane&15, row = (lane>>4)*4 + reg
  const int cl = lane & 15;
  const int rg = lane >> 4;
#pragma unroll
  for (int m = 0; m < 8; ++m) {
    int grow = bm0 + ((m >> 2) << 7) + wm64 + ((m & 3) << 4) + rg * 4;
#pragma unroll
    for (int n = 0; n < 4; ++n) {
      int col = bn0 + ((n >> 1) << 7) + wn32 + ((n & 1) << 4) + cl;
      float bv = bias[col];
#pragma unroll
      for (int r = 0; r < 4; ++r) {
        size_t o = (size_t)(grow + r) * N + col;
        float v = acc[m][n][r] + bv;
        if (EPI == 0) {
          float g = 0.5f * v * (1.f + erff(v * 0.70710678118654752f));
          ((bf16*)outv)[o] = __float2bfloat16(g);
        } else {
          ((float*)outv)[o] = v;
        }
      }
    }
  }
}

extern "C" void kernel_launch(void* const* d_in, const int* in_sizes, int n_in,
                              void* d_out, int out_size, void* d_ws,
                              size_t ws_size, hipStream_t stream) {
  const int* idx = (const int*)d_in[0];       // [B,L]
  const float* Mlog = (const float*)d_in[1];  // [V,V]
  const float* W1 = (const float*)d_in[2];    // [V,2V]
  const float* b1 = (const float*)d_in[3];    // [2V]
  const float* W2 = (const float*)d_in[4];    // [2V,V]
  const float* b2 = (const float*)d_in[5];    // [V]
  float* out = (float*)d_out;                 // [B,L,V] f32

  char* ws = (char*)d_ws;
  const size_t MB64 = 64ull << 20;
  bf16* ctx = (bf16*)ws;             // 64 MiB  [8192][4096] (dead after GEMM1)
  bf16* W2t = (bf16*)ws;             // aliases ctx: [4096][8192]
  bf16* W1t = (bf16*)(ws + MB64);    // 64 MiB  [8192][4096]
  bf16* h = (bf16*)(ws + 2 * MB64);  // 128 MiB [8192][8192]
  float* segsum = (float*)h;         // 1 MiB, dead before GEMM1 writes h
  (void)ws_size;

  dim3 tb(32, 8);
  // W1^T cast
  transpose_f32_bf16<<<dim3(8192 / 32, 4096 / 32), tb, 0, stream>>>(W1, W1t,
                                                                    4096, 8192);
  // ctx = causal-mean(sigmoid(M)[idx]), segment-parallel two-pass
  ctx_partial<<<BB * 16 * SEG, 256, 0, stream>>>(idx, Mlog, segsum);
  ctx_final<<<BB * 16 * SEG, 256, 0, stream>>>(idx, Mlog, segsum, ctx);
  // h = gelu(ctx @ W1 + b1)  -> bf16
  gemm256<0><<<(8192 / 256) * (8192 / 256), 512, 0, stream>>>(
      ctx, W1t, b1, h, 8192, 8192, 4096);
  // W2^T cast (reuses ctx space)
  transpose_f32_bf16<<<dim3(4096 / 32, 8192 / 32), tb, 0, stream>>>(W2, W2t,
                                                                    8192, 4096);
  // out = h @ W2 + b2  -> f32
  gemm256<1><<<(8192 / 256) * (4096 / 256), 512, 0, stream>>>(
      h, W2t, b2, out, 8192, 4096, 8192);
}

// Round 6
// 2413.318 us; speedup vs baseline: 1.5185x; 1.5185x over previous
//
#include <hip/hip_runtime.h>
#include <hip/hip_bf16.h>

#define VOCAB 4096
#define BB 4
#define LL 2048
#define SEG 16
#define SEGL 128  // LL/SEG

typedef __hip_bfloat16 bf16;
typedef __bf16 bf16x8 __attribute__((ext_vector_type(8)));
typedef float f32x4 __attribute__((ext_vector_type(4)));

__device__ __forceinline__ void gload16(const void* g, void* l) {
  __builtin_amdgcn_global_load_lds(
      (const __attribute__((address_space(1))) unsigned int*)g,
      (__attribute__((address_space(3))) unsigned int*)l, 16, 0, 0);
}

// ---------------- transpose f32 [K][N] -> bf16 [N][K] ----------------
__global__ void transpose_f32_bf16(const float* __restrict__ in,
                                   bf16* __restrict__ out, int K, int N) {
  __shared__ float tile[32][33];
  int bx = blockIdx.x;  // tile along N
  int by = blockIdx.y;  // tile along K
  int x = bx * 32 + threadIdx.x;
#pragma unroll
  for (int i = threadIdx.y; i < 32; i += 8)
    tile[i][threadIdx.x] = in[(size_t)(by * 32 + i) * N + x];
  __syncthreads();
  int k = by * 32 + threadIdx.x;
#pragma unroll
  for (int i = threadIdx.y; i < 32; i += 8)
    out[(size_t)(bx * 32 + i) * K + k] = __float2bfloat16(tile[threadIdx.x][i]);
}

// -------- ctx pass A: per-segment sigmoid column sums --------
__global__ void ctx_partial(const int* __restrict__ idx,
                            const float* __restrict__ Mlog,
                            float* __restrict__ segsum) {
  int b = blockIdx.x / (16 * SEG);
  int rem = blockIdx.x % (16 * SEG);
  int chunk = rem / SEG;
  int s = rem % SEG;
  int col = chunk * 256 + threadIdx.x;
  __shared__ int sidx[SEGL];
  if (threadIdx.x < SEGL)
    sidx[threadIdx.x] = idx[b * LL + s * SEGL + threadIdx.x];
  __syncthreads();
  const float* base = Mlog + col;
  float a0 = 0.f, a1 = 0.f, a2 = 0.f, a3 = 0.f;
#pragma unroll 4
  for (int t = 0; t < SEGL; t += 4) {
    float v0 = base[(size_t)sidx[t + 0] * VOCAB];
    float v1 = base[(size_t)sidx[t + 1] * VOCAB];
    float v2 = base[(size_t)sidx[t + 2] * VOCAB];
    float v3 = base[(size_t)sidx[t + 3] * VOCAB];
    a0 += 1.f / (1.f + __expf(-v0));
    a1 += 1.f / (1.f + __expf(-v1));
    a2 += 1.f / (1.f + __expf(-v2));
    a3 += 1.f / (1.f + __expf(-v3));
  }
  segsum[(size_t)blockIdx.x * 256 + threadIdx.x] = (a0 + a1) + (a2 + a3);
}

// -------- ctx pass B: replay segment with offset, write running mean --------
__global__ void ctx_final(const int* __restrict__ idx,
                          const float* __restrict__ Mlog,
                          const float* __restrict__ segsum,
                          bf16* __restrict__ ctx) {
  int b = blockIdx.x / (16 * SEG);
  int rem = blockIdx.x % (16 * SEG);
  int chunk = rem / SEG;
  int s = rem % SEG;
  int col = chunk * 256 + threadIdx.x;
  __shared__ int sidx[SEGL];
  if (threadIdx.x < SEGL)
    sidx[threadIdx.x] = idx[b * LL + s * SEGL + threadIdx.x];
  __syncthreads();
  const float* ss = segsum + (size_t)((b * 16 + chunk) * SEG) * 256 + threadIdx.x;
  float acc = 0.f;
  for (int s2 = 0; s2 < s; ++s2) acc += ss[(size_t)s2 * 256];
  const float* base = Mlog + col;
  bf16* outp = ctx + ((size_t)b * LL + (size_t)s * SEGL) * VOCAB + col;
#pragma unroll 8
  for (int t = 0; t < SEGL; ++t) {
    float v = base[(size_t)sidx[t] * VOCAB];
    acc += 1.f / (1.f + __expf(-v));
    float inv = __fdividef(1.f, (float)(s * SEGL + t + 1));
    outp[(size_t)t * VOCAB] = __float2bfloat16(acc * inv);
  }
}

// ---------------- 256x256 bf16 GEMM, register-rotation read-skew ---------
// 512 thr (2x4 waves), BK=64, 128KiB LDS dbuf, chunk-XOR swizzle.
// Fragment budget 96 VGPR (A0,A1 32 each; BX,BY 16 each) so arch VGPR fits
// the 128 cap left by the 128-AGPR accumulator (round-4/5 lesson: 512-thr
// block => hard 256 unified regs/wave; 112-reg fragment set spilled).
// Roles rotate by tile parity: ph1 reads b1_t into the slot freed by prev
// ph4; ph3 refills A0 with next tile's A0; ph4 reads b0_{t+1} into the slot
// dead after ph3. MFMA waits only the PREVIOUS phase's ds_reads (counted
// LGKM 4/8/8/12) so LDS service overlaps MFMA; VMW(2) everywhere (2-phase
// stage->read cover). EPI==0: bf16 gelu_exact(C); EPI==1: f32 C.

#define BAR() asm volatile("s_barrier" ::: "memory")
#define LGKM(n_) asm volatile("s_waitcnt lgkmcnt(" #n_ ")" ::: "memory")
#define VMW(n_) asm volatile("s_waitcnt vmcnt(" #n_ ")" ::: "memory")
#define SB0() __builtin_amdgcn_sched_barrier(0)
#define P1() __builtin_amdgcn_s_setprio(1)
#define P0() __builtin_amdgcn_s_setprio(0)

// stage one half-tile (128 rows x 64 cols) of A or B into buffer b
#define STG_A(t_, h_, b_)                                           \
  {                                                                 \
    const bf16* s_ = Asrc + (size_t)(h_)*128 * K + (size_t)(t_)*64; \
    bf16* d_ = sm + (b_)*32768 + (h_)*8192 + wave * 512;            \
    gload16(s_, d_);                                                \
    gload16(s_ + rowK64, d_ + 4096);                                \
  }
#define STG_B(t_, h_, b_)                                           \
  {                                                                 \
    const bf16* s_ = Bsrc + (size_t)(h_)*128 * K + (size_t)(t_)*64; \
    bf16* d_ = sm + (b_)*32768 + 16384 + (h_)*8192 + wave * 512;    \
    gload16(s_, d_);                                                \
    gload16(s_ + rowK64, d_ + 4096);                                \
  }

// fragment load: slot = row*8 + (kc ^ (row&7)); row&7 == rsel&7 == xorv
#define LDF(base_, row_, kc_) \
  (*(const bf16x8*)((base_) + (row_)*64 + ((((kc_) ^ xorv)) << 3)))

#define RD_A(dst_, base_, mh_)                       \
  _Pragma("unroll") for (int i_ = 0; i_ < 4; ++i_) { \
    int row_ = (mh_)*128 + wm64 + i_ * 16 + rsel;    \
    dst_[i_][0] = LDF(base_, row_, ksel);            \
    dst_[i_][1] = LDF(base_, row_, 4 + ksel);        \
  }
#define RD_B(dst_, base_, nh_)                       \
  _Pragma("unroll") for (int j_ = 0; j_ < 2; ++j_) { \
    int row_ = (nh_)*128 + wn32 + j_ * 16 + rsel;    \
    dst_[j_][0] = LDF(base_, row_, ksel);            \
    dst_[j_][1] = LDF(base_, row_, 4 + ksel);        \
  }

#define MQ(mh_, nh_, A_, B_)                                              \
  _Pragma("unroll") for (int i_ = 0; i_ < 4; ++i_)                        \
      _Pragma("unroll") for (int j_ = 0; j_ < 2; ++j_) {                  \
    f32x4& c_ = acc[(mh_)*4 + i_][(nh_)*2 + j_];                          \
    c_ = __builtin_amdgcn_mfma_f32_16x16x32_bf16(A_[i_][0], B_[j_][0],    \
                                                 c_, 0, 0, 0);            \
    c_ = __builtin_amdgcn_mfma_f32_16x16x32_bf16(A_[i_][1], B_[j_][1],    \
                                                 c_, 0, 0, 0);            \
  }

// One K-tile. T_: tile index, bc_: current buffer (literal 0/1),
// Bb0_: regs holding b0_t (read during prev ph4); Bb1_: slot for b1_t,
// refilled with b0_{t+1} in ph4 (becomes next tile's Bb0_).
#define TILE_BODY(T_, bc_, Bb0_, Bb1_)                              \
  {                                                                 \
    const bf16* Ab = sm + (bc_)*32768;                              \
    const bf16* Bb = Ab + 16384;                                    \
    const bf16* Abn = sm + ((bc_) ^ 1) * 32768;                     \
    const bf16* Bbn = Abn + 16384;                                  \
    /* ph1: rd b1_t -> Bb1; stg A(t+1,h0); MFMA (0,0)=A0 x Bb0 */   \
    VMW(2);                                                         \
    BAR();                                                          \
    RD_B(Bb1_, Bb, 1);                                              \
    if ((T_) + 1 < NT) STG_A((T_) + 1, 0, (bc_) ^ 1);               \
    BAR();                                                          \
    LGKM(4);                                                        \
    SB0();                                                          \
    P1();                                                           \
    MQ(0, 0, A0, Bb0_);                                             \
    P0();                                                           \
    /* ph2: rd A1_t; stg B(t+1,h0); MFMA (0,1)=A0 x Bb1 */          \
    if ((T_) + 1 < NT) { VMW(2); } else { VMW(0); }                 \
    BAR();                                                          \
    RD_A(A1, Ab, 1);                                                \
    if ((T_) + 1 < NT) STG_B((T_) + 1, 0, (bc_) ^ 1);               \
    BAR();                                                          \
    LGKM(8);                                                        \
    SB0();                                                          \
    P1();                                                           \
    MQ(0, 1, A0, Bb1_);                                             \
    P0();                                                           \
    /* ph3: rd A0 <- A(t+1,h0) (A0 dead); stg B(t+1,h1); (1,1) */   \
    if ((T_) + 1 < NT) { VMW(2); }                                  \
    BAR();                                                          \
    if ((T_) + 1 < NT) {                                            \
      RD_A(A0, Abn, 0);                                             \
      STG_B((T_) + 1, 1, (bc_) ^ 1);                                \
    }                                                               \
    BAR();                                                          \
    if ((T_) + 1 < NT) { LGKM(8); } else { LGKM(0); }               \
    SB0();                                                          \
    P1();                                                           \
    MQ(1, 1, A1, Bb1_);                                             \
    P0();                                                           \
    /* ph4: rd b0_{t+1} -> Bb1 (dead); stg A(t+1,h1); (1,0) */      \
    if ((T_) + 1 < NT) { VMW(2); }                                  \
    BAR();                                                          \
    if ((T_) + 1 < NT) {                                            \
      RD_B(Bb1_, Bbn, 0);                                           \
      STG_A((T_) + 1, 1, (bc_) ^ 1);                                \
    }                                                               \
    BAR();                                                          \
    if ((T_) + 1 < NT) { LGKM(12); } else { LGKM(0); }              \
    SB0();                                                          \
    P1();                                                           \
    MQ(1, 0, A1, Bb0_);                                             \
    P0();                                                           \
  }

template <int EPI>
__global__ __launch_bounds__(512, 1) void gemm256(const bf16* __restrict__ A,
                                                  const bf16* __restrict__ Bt,
                                                  const float* __restrict__ bias,
                                                  void* __restrict__ outv,
                                                  int M, int N, int K) {
  __shared__ __align__(16) bf16 sm[65536];  // 128 KiB: 2 x (A 32KB | B 32KB)
  const int tid = threadIdx.x;
  const int wave = tid >> 6;
  const int lane = tid & 63;
  const int nwg = gridDim.x;
  const int bid = blockIdx.x;
  const int swz = (bid & 7) * (nwg >> 3) + (bid >> 3);  // nwg % 8 == 0
  const int gn = N >> 8;
  const int bm0 = (swz / gn) << 8;
  const int bn0 = (swz % gn) << 8;
  const int wm64 = (wave >> 2) << 6;  // wave_m * 64
  const int wn32 = (wave & 3) << 5;   // wave_n * 32
  const int rsel = lane & 15;
  const int ksel = lane >> 4;
  const int xorv = rsel & 7;

  // staging source: thread covers slots tid and tid+512 of each half-tile;
  // slot p -> row=p>>3, kc=(p&7)^(row&7)
  const int r0 = tid >> 3;
  const int kc0 = (tid & 7) ^ (r0 & 7);
  const bf16* Asrc = A + (size_t)(bm0 + r0) * K + kc0 * 8;
  const bf16* Bsrc = Bt + (size_t)(bn0 + r0) * K + kc0 * 8;
  const size_t rowK64 = (size_t)64 * K;
  const int NT = K >> 6;

  f32x4 acc[8][4];
#pragma unroll
  for (int i = 0; i < 8; ++i)
#pragma unroll
    for (int j = 0; j < 4; ++j) acc[i][j] = (f32x4){0.f, 0.f, 0.f, 0.f};

  bf16x8 A0[4][2], A1[4][2], BX[2][2], BY[2][2];

  // prologue: stage tile0 {A0h,B0h,B1h,A1h} -> buf0
  STG_A(0, 0, 0);
  STG_B(0, 0, 0);
  STG_B(0, 1, 0);
  STG_A(0, 1, 0);
  VMW(4);  // A h0, B h0 landed; B h1, A h1 still in flight
  BAR();
  RD_A(A0, sm, 0);
  RD_B(BX, sm + 16384, 0);

  for (int t = 0; t < NT; t += 2) {
    TILE_BODY(t, 0, BX, BY);
    TILE_BODY(t + 1, 1, BY, BX);
  }

  // epilogue; C/D layout: col = lane&15, row = (lane>>4)*4 + reg
  const int cl = lane & 15;
  const int rg = lane >> 4;
#pragma unroll
  for (int m = 0; m < 8; ++m) {
    int grow = bm0 + ((m >> 2) << 7) + wm64 + ((m & 3) << 4) + rg * 4;
#pragma unroll
    for (int n = 0; n < 4; ++n) {
      int col = bn0 + ((n >> 1) << 7) + wn32 + ((n & 1) << 4) + cl;
      float bv = bias[col];
#pragma unroll
      for (int r = 0; r < 4; ++r) {
        size_t o = (size_t)(grow + r) * N + col;
        float v = acc[m][n][r] + bv;
        if (EPI == 0) {
          float g = 0.5f * v * (1.f + erff(v * 0.70710678118654752f));
          ((bf16*)outv)[o] = __float2bfloat16(g);
        } else {
          ((float*)outv)[o] = v;
        }
      }
    }
  }
}

extern "C" void kernel_launch(void* const* d_in, const int* in_sizes, int n_in,
                              void* d_out, int out_size, void* d_ws,
                              size_t ws_size, hipStream_t stream) {
  const int* idx = (const int*)d_in[0];       // [B,L]
  const float* Mlog = (const float*)d_in[1];  // [V,V]
  const float* W1 = (const float*)d_in[2];    // [V,2V]
  const float* b1 = (const float*)d_in[3];    // [2V]
  const float* W2 = (const float*)d_in[4];    // [2V,V]
  const float* b2 = (const float*)d_in[5];    // [V]
  float* out = (float*)d_out;                 // [B,L,V] f32

  char* ws = (char*)d_ws;
  const size_t MB64 = 64ull << 20;
  bf16* ctx = (bf16*)ws;             // 64 MiB  [8192][4096] (dead after GEMM1)
  bf16* W2t = (bf16*)ws;             // aliases ctx: [4096][8192]
  bf16* W1t = (bf16*)(ws + MB64);    // 64 MiB  [8192][4096]
  bf16* h = (bf16*)(ws + 2 * MB64);  // 128 MiB [8192][8192]
  float* segsum = (float*)h;         // 1 MiB, dead before GEMM1 writes h
  (void)ws_size;

  dim3 tb(32, 8);
  // W1^T cast
  transpose_f32_bf16<<<dim3(8192 / 32, 4096 / 32), tb, 0, stream>>>(W1, W1t,
                                                                    4096, 8192);
  // ctx = causal-mean(sigmoid(M)[idx]), segment-parallel two-pass
  ctx_partial<<<BB * 16 * SEG, 256, 0, stream>>>(idx, Mlog, segsum);
  ctx_final<<<BB * 16 * SEG, 256, 0, stream>>>(idx, Mlog, segsum, ctx);
  // h = gelu(ctx @ W1 + b1)  -> bf16
  gemm256<0><<<(8192 / 256) * (8192 / 256), 512, 0, stream>>>(
      ctx, W1t, b1, h, 8192, 8192, 4096);
  // W2^T cast (reuses ctx space)
  transpose_f32_bf16<<<dim3(4096 / 32, 8192 / 32), tb, 0, stream>>>(W2, W2t,
                                                                    8192, 4096);
  // out = h @ W2 + b2  -> f32
  gemm256<1><<<(8192 / 256) * (4096 / 256), 512, 0, stream>>>(
      h, W2t, b2, out, 8192, 4096, 8192);
}

// Round 7
// 1117.676 us; speedup vs baseline: 3.2787x; 2.1592x over previous
//
#include <hip/hip_runtime.h>
#include <hip/hip_bf16.h>

#define VOCAB 4096
#define BB 4
#define LL 2048
#define SEG 16
#define SEGL 128  // LL/SEG

typedef __hip_bfloat16 bf16;
typedef __bf16 bf16x8 __attribute__((ext_vector_type(8)));
typedef float f32x4 __attribute__((ext_vector_type(4)));

__device__ __forceinline__ void gload16(const void* g, void* l) {
  __builtin_amdgcn_global_load_lds(
      (const __attribute__((address_space(1))) unsigned int*)g,
      (__attribute__((address_space(3))) unsigned int*)l, 16, 0, 0);
}

__device__ __forceinline__ bf16x8 as_bf(f32x4 v) {
  union { f32x4 f; bf16x8 b; } u;
  u.f = v;
  return u.b;
}

// ---------------- transpose f32 [K][N] -> bf16 [N][K] ----------------
__global__ void transpose_f32_bf16(const float* __restrict__ in,
                                   bf16* __restrict__ out, int K, int N) {
  __shared__ float tile[32][33];
  int bx = blockIdx.x;  // tile along N
  int by = blockIdx.y;  // tile along K
  int x = bx * 32 + threadIdx.x;
#pragma unroll
  for (int i = threadIdx.y; i < 32; i += 8)
    tile[i][threadIdx.x] = in[(size_t)(by * 32 + i) * N + x];
  __syncthreads();
  int k = by * 32 + threadIdx.x;
#pragma unroll
  for (int i = threadIdx.y; i < 32; i += 8)
    out[(size_t)(bx * 32 + i) * K + k] = __float2bfloat16(tile[threadIdx.x][i]);
}

// -------- ctx pass A: per-segment sigmoid column sums --------
__global__ void ctx_partial(const int* __restrict__ idx,
                            const float* __restrict__ Mlog,
                            float* __restrict__ segsum) {
  int b = blockIdx.x / (16 * SEG);
  int rem = blockIdx.x % (16 * SEG);
  int chunk = rem / SEG;
  int s = rem % SEG;
  int col = chunk * 256 + threadIdx.x;
  __shared__ int sidx[SEGL];
  if (threadIdx.x < SEGL)
    sidx[threadIdx.x] = idx[b * LL + s * SEGL + threadIdx.x];
  __syncthreads();
  const float* base = Mlog + col;
  float a0 = 0.f, a1 = 0.f, a2 = 0.f, a3 = 0.f;
#pragma unroll 4
  for (int t = 0; t < SEGL; t += 4) {
    float v0 = base[(size_t)sidx[t + 0] * VOCAB];
    float v1 = base[(size_t)sidx[t + 1] * VOCAB];
    float v2 = base[(size_t)sidx[t + 2] * VOCAB];
    float v3 = base[(size_t)sidx[t + 3] * VOCAB];
    a0 += 1.f / (1.f + __expf(-v0));
    a1 += 1.f / (1.f + __expf(-v1));
    a2 += 1.f / (1.f + __expf(-v2));
    a3 += 1.f / (1.f + __expf(-v3));
  }
  segsum[(size_t)blockIdx.x * 256 + threadIdx.x] = (a0 + a1) + (a2 + a3);
}

// -------- ctx pass B: replay segment with offset, write running mean --------
__global__ void ctx_final(const int* __restrict__ idx,
                          const float* __restrict__ Mlog,
                          const float* __restrict__ segsum,
                          bf16* __restrict__ ctx) {
  int b = blockIdx.x / (16 * SEG);
  int rem = blockIdx.x % (16 * SEG);
  int chunk = rem / SEG;
  int s = rem % SEG;
  int col = chunk * 256 + threadIdx.x;
  __shared__ int sidx[SEGL];
  if (threadIdx.x < SEGL)
    sidx[threadIdx.x] = idx[b * LL + s * SEGL + threadIdx.x];
  __syncthreads();
  const float* ss = segsum + (size_t)((b * 16 + chunk) * SEG) * 256 + threadIdx.x;
  float acc = 0.f;
  for (int s2 = 0; s2 < s; ++s2) acc += ss[(size_t)s2 * 256];
  const float* base = Mlog + col;
  bf16* outp = ctx + ((size_t)b * LL + (size_t)s * SEGL) * VOCAB + col;
#pragma unroll 8
  for (int t = 0; t < SEGL; ++t) {
    float v = base[(size_t)sidx[t] * VOCAB];
    acc += 1.f / (1.f + __expf(-v));
    float inv = __fdividef(1.f, (float)(s * SEGL + t + 1));
    outp[(size_t)t * VOCAB] = __float2bfloat16(acc * inv);
  }
}

// ---------------- 256x256 bf16 GEMM — round-2 skeleton, asm ds_read -------
// 512 thr (2x4 waves), BK=64, 128KiB LDS dbuf, chunk-XOR swizzle (0 confl).
// ALL LDS reads are inline-asm ds_read_b128 (opaque to the compiler's
// memory legalizer) so no conservative vmcnt(0) waits are inserted against
// the global_load_lds DMA; the ONLY waits are: VMW(4) at tile top (drains
// exactly tile t's 4 half-tiles; leaves t+1 prefetch in flight) and
// per-phase LGKM(0)+sched_barrier(0) before the MFMA cluster (rule #18).
// Staging map (= round 2): ph1->A(t+1,h1,bo), ph2->B(t+1,h0,bo),
// ph3->A(t+2,h0,bc), ph4->B(t+2,h1,bc). Frags: af[4][2], bX, bY (64 VGPR
// in-phase, no cross-phase holding -> no spills at the 128-VGPR cap).
// EPI==0: out = bf16 gelu_exact(C)   EPI==1: out = f32 C

#define BAR() asm volatile("s_barrier" ::: "memory")
#define LGKM0() asm volatile("s_waitcnt lgkmcnt(0)" ::: "memory")
#define VMW(n_) asm volatile("s_waitcnt vmcnt(" #n_ ")" ::: "memory")
#define SB0() __builtin_amdgcn_sched_barrier(0)
#define P1() __builtin_amdgcn_s_setprio(1)
#define P0() __builtin_amdgcn_s_setprio(0)

#define STG_A(t_, h_, b_)                                           \
  {                                                                 \
    const bf16* s_ = Asrc + (size_t)(h_)*128 * K + (size_t)(t_)*64; \
    bf16* d_ = sm + (b_)*32768 + (h_)*8192 + wave * 512;            \
    gload16(s_, d_);                                                \
    gload16(s_ + rowK64, d_ + 4096);                                \
  }
#define STG_B(t_, h_, b_)                                           \
  {                                                                 \
    const bf16* s_ = Bsrc + (size_t)(h_)*128 * K + (size_t)(t_)*64; \
    bf16* d_ = sm + (b_)*32768 + 16384 + (h_)*8192 + wave * 512;    \
    gload16(s_, d_);                                                \
    gload16(s_ + rowK64, d_ + 4096);                                \
  }

// one asm LDS read: 16B into a f32x4, literal byte offset
#define RD1(dst_, base_, off_)                       \
  asm volatile("ds_read_b128 %0, %1 offset:%2"       \
               : "=v"(dst_)                          \
               : "v"(base_), "i"(off_)               \
               : "memory")

// A quadrant mh_: 8 reads (4 m-frags x 2 k-chunks); bases hold kc0/kc1 terms
#define RD_A(b0_, b1_, mh_)                    \
  RD1(af[0][0], b0_, (mh_)*16384 + 0);         \
  RD1(af[0][1], b1_, (mh_)*16384 + 0);         \
  RD1(af[1][0], b0_, (mh_)*16384 + 2048);      \
  RD1(af[1][1], b1_, (mh_)*16384 + 2048);      \
  RD1(af[2][0], b0_, (mh_)*16384 + 4096);      \
  RD1(af[2][1], b1_, (mh_)*16384 + 4096);      \
  RD1(af[3][0], b0_, (mh_)*16384 + 6144);      \
  RD1(af[3][1], b1_, (mh_)*16384 + 6144);

// B quadrant nh_ into dst_ (bX or bY): 4 reads
#define RD_B(dst_, b0_, b1_, nh_)              \
  RD1(dst_[0][0], b0_, (nh_)*16384 + 0);       \
  RD1(dst_[0][1], b1_, (nh_)*16384 + 0);       \
  RD1(dst_[1][0], b0_, (nh_)*16384 + 2048);    \
  RD1(dst_[1][1], b1_, (nh_)*16384 + 2048);

#define MQ(mh_, nh_, B_)                                                     \
  _Pragma("unroll") for (int i_ = 0; i_ < 4; ++i_)                           \
      _Pragma("unroll") for (int j_ = 0; j_ < 2; ++j_) {                     \
    f32x4& c_ = acc[(mh_)*4 + i_][(nh_)*2 + j_];                             \
    c_ = __builtin_amdgcn_mfma_f32_16x16x32_bf16(as_bf(af[i_][0]),           \
                                                 as_bf(B_[j_][0]), c_, 0, 0, \
                                                 0);                         \
    c_ = __builtin_amdgcn_mfma_f32_16x16x32_bf16(as_bf(af[i_][1]),           \
                                                 as_bf(B_[j_][1]), c_, 0, 0, \
                                                 0);                         \
  }

#define TILE_BODY(T_, aK0_, aK1_, bK0_, bK1_, bc_)   \
  {                                                  \
    if ((T_) + 1 < NT) { VMW(4); } else { VMW(0); }  \
    BAR();                                           \
    /* ph1: rd A0,B0 ; stg A(t+1,h1) ; MFMA (0,0) */ \
    RD_A(aK0_, aK1_, 0);                             \
    RD_B(bX, bK0_, bK1_, 0);                         \
    if ((T_) + 1 < NT) STG_A((T_) + 1, 1, (bc_) ^ 1);\
    BAR();                                           \
    LGKM0();                                         \
    SB0();                                           \
    P1(); MQ(0, 0, bX); P0();                        \
    BAR();                                           \
    /* ph2: rd B1 ; stg B(t+1,h0) ; MFMA (0,1) */    \
    RD_B(bY, bK0_, bK1_, 1);                         \
    if ((T_) + 1 < NT) STG_B((T_) + 1, 0, (bc_) ^ 1);\
    BAR();                                           \
    LGKM0();                                         \
    SB0();                                           \
    P1(); MQ(0, 1, bY); P0();                        \
    BAR();                                           \
    /* ph3: rd A1 ; stg A(t+2,h0) ; MFMA (1,1) */    \
    RD_A(aK0_, aK1_, 1);                             \
    if ((T_) + 2 < NT) STG_A((T_) + 2, 0, (bc_));    \
    BAR();                                           \
    LGKM0();                                         \
    SB0();                                           \
    P1(); MQ(1, 1, bY); P0();                        \
    BAR();                                           \
    /* ph4: rd B0 ; stg B(t+2,h1) ; MFMA (1,0) */    \
    RD_B(bX, bK0_, bK1_, 0);                         \
    if ((T_) + 2 < NT) STG_B((T_) + 2, 1, (bc_));    \
    BAR();                                           \
    LGKM0();                                         \
    SB0();                                           \
    P1(); MQ(1, 0, bX); P0();                        \
    BAR();                                           \
  }

template <int EPI>
__global__ __launch_bounds__(512) void gemm256(const bf16* __restrict__ A,
                                               const bf16* __restrict__ Bt,
                                               const float* __restrict__ bias,
                                               void* __restrict__ outv, int M,
                                               int N, int K) {
  __shared__ __align__(16) bf16 sm[65536];  // 128 KiB: 2 x (A 32KB | B 32KB)
  const int tid = threadIdx.x;
  const int wave = tid >> 6;
  const int lane = tid & 63;
  const int nwg = gridDim.x;
  const int bid = blockIdx.x;
  const int swz = (bid & 7) * (nwg >> 3) + (bid >> 3);  // nwg % 8 == 0
  const int gn = N >> 8;
  const int bm0 = (swz / gn) << 8;
  const int bn0 = (swz % gn) << 8;
  const int wm64 = (wave >> 2) << 6;  // wave_m * 64
  const int wn32 = (wave & 3) << 5;   // wave_n * 32
  const int rsel = lane & 15;
  const int ksel = lane >> 4;
  const int xorv = rsel & 7;

  // staging source: thread covers slots tid and tid+512 of each half-tile;
  // slot p -> row=p>>3, kc=(p&7)^(row&7)
  const int r0 = tid >> 3;
  const int kc0 = (tid & 7) ^ (r0 & 7);
  const bf16* Asrc = A + (size_t)(bm0 + r0) * K + kc0 * 8;
  const bf16* Bsrc = Bt + (size_t)(bn0 + r0) * K + kc0 * 8;
  const size_t rowK64 = (size_t)64 * K;
  const int NT = K >> 6;

  // 32-bit LDS byte bases for asm ds_read (chunk-XOR folded in)
  const unsigned smbase =
      (unsigned)(unsigned long long)(__attribute__((address_space(3)))
                                     bf16*)sm;
  const unsigned kT0 = (unsigned)((ksel ^ xorv) << 4);
  const unsigned kT1 = (unsigned)(((ksel + 4) ^ xorv) << 4);
  const unsigned aRow = (unsigned)((wm64 + rsel) * 128);
  const unsigned bRow = (unsigned)((wn32 + rsel) * 128);
  const unsigned a00 = smbase + aRow + kT0;
  const unsigned a10 = smbase + aRow + kT1;
  const unsigned b00 = smbase + 32768u + bRow + kT0;
  const unsigned b10 = smbase + 32768u + bRow + kT1;
  const unsigned a01 = a00 + 65536u, a11 = a10 + 65536u;
  const unsigned b01 = b00 + 65536u, b11 = b10 + 65536u;

  f32x4 acc[8][4];
#pragma unroll
  for (int i = 0; i < 8; ++i)
#pragma unroll
    for (int j = 0; j < 4; ++j) acc[i][j] = (f32x4){0.f, 0.f, 0.f, 0.f};

  f32x4 af[4][2], bX[2][2], bY[2][2];

  // prologue FIFO: [A0(0),B1(0),A1(0),B0(0),A0(1),B1(1)] (12 gload16)
  STG_A(0, 0, 0);
  STG_B(0, 1, 0);
  STG_A(0, 1, 0);
  STG_B(0, 0, 0);
  STG_A(1, 0, 1);
  STG_B(1, 1, 1);

  for (int t = 0; t < NT; t += 2) {
    TILE_BODY(t, a00, a10, b00, b10, 0);
    TILE_BODY(t + 1, a01, a11, b01, b11, 1);
  }

  // epilogue; C/D layout: col = lane&15, row = (lane>>4)*4 + reg
  const int cl = lane & 15;
  const int rg = lane >> 4;
#pragma unroll
  for (int m = 0; m < 8; ++m) {
    int grow = bm0 + ((m >> 2) << 7) + wm64 + ((m & 3) << 4) + rg * 4;
#pragma unroll
    for (int n = 0; n < 4; ++n) {
      int col = bn0 + ((n >> 1) << 7) + wn32 + ((n & 1) << 4) + cl;
      float bv = bias[col];
#pragma unroll
      for (int r = 0; r < 4; ++r) {
        size_t o = (size_t)(grow + r) * N + col;
        float v = acc[m][n][r] + bv;
        if (EPI == 0) {
          float g = 0.5f * v * (1.f + erff(v * 0.70710678118654752f));
          ((bf16*)outv)[o] = __float2bfloat16(g);
        } else {
          ((float*)outv)[o] = v;
        }
      }
    }
  }
}

extern "C" void kernel_launch(void* const* d_in, const int* in_sizes, int n_in,
                              void* d_out, int out_size, void* d_ws,
                              size_t ws_size, hipStream_t stream) {
  const int* idx = (const int*)d_in[0];       // [B,L]
  const float* Mlog = (const float*)d_in[1];  // [V,V]
  const float* W1 = (const float*)d_in[2];    // [V,2V]
  const float* b1 = (const float*)d_in[3];    // [2V]
  const float* W2 = (const float*)d_in[4];    // [2V,V]
  const float* b2 = (const float*)d_in[5];    // [V]
  float* out = (float*)d_out;                 // [B,L,V] f32

  char* ws = (char*)d_ws;
  const size_t MB64 = 64ull << 20;
  bf16* ctx = (bf16*)ws;             // 64 MiB  [8192][4096] (dead after GEMM1)
  bf16* W2t = (bf16*)ws;             // aliases ctx: [4096][8192]
  bf16* W1t = (bf16*)(ws + MB64);    // 64 MiB  [8192][4096]
  bf16* h = (bf16*)(ws + 2 * MB64);  // 128 MiB [8192][8192]
  float* segsum = (float*)h;         // 1 MiB, dead before GEMM1 writes h
  (void)ws_size;

  dim3 tb(32, 8);
  // W1^T cast
  transpose_f32_bf16<<<dim3(8192 / 32, 4096 / 32), tb, 0, stream>>>(W1, W1t,
                                                                    4096, 8192);
  // ctx = causal-mean(sigmoid(M)[idx]), segment-parallel two-pass
  ctx_partial<<<BB * 16 * SEG, 256, 0, stream>>>(idx, Mlog, segsum);
  ctx_final<<<BB * 16 * SEG, 256, 0, stream>>>(idx, Mlog, segsum, ctx);
  // h = gelu(ctx @ W1 + b1)  -> bf16
  gemm256<0><<<(8192 / 256) * (8192 / 256), 512, 0, stream>>>(
      ctx, W1t, b1, h, 8192, 8192, 4096);
  // W2^T cast (reuses ctx space)
  transpose_f32_bf16<<<dim3(4096 / 32, 8192 / 32), tb, 0, stream>>>(W2, W2t,
                                                                    8192, 4096);
  // out = h @ W2 + b2  -> f32
  gemm256<1><<<(8192 / 256) * (4096 / 256), 512, 0, stream>>>(
      h, W2t, b2, out, 8192, 4096, 8192);
}

// Round 8
// 994.423 us; speedup vs baseline: 3.6851x; 1.1239x over previous
//
#include <hip/hip_runtime.h>
#include <hip/hip_bf16.h>

#define VOCAB 4096
#define BB 4
#define LL 2048
#define SEG 16
#define SEGL 128  // LL/SEG

typedef __hip_bfloat16 bf16;
typedef __bf16 bf16x8 __attribute__((ext_vector_type(8)));
typedef float f32x4 __attribute__((ext_vector_type(4)));

__device__ __forceinline__ void gload16(const void* g, void* l) {
  __builtin_amdgcn_global_load_lds(
      (const __attribute__((address_space(1))) unsigned int*)g,
      (__attribute__((address_space(3))) unsigned int*)l, 16, 0, 0);
}

__device__ __forceinline__ bf16x8 as_bf(f32x4 v) {
  union { f32x4 f; bf16x8 b; } u;
  u.f = v;
  return u.b;
}

// ---------------- transpose f32 [K][N] -> bf16 [N][K] ----------------
__global__ void transpose_f32_bf16(const float* __restrict__ in,
                                   bf16* __restrict__ out, int K, int N) {
  __shared__ float tile[32][33];
  int bx = blockIdx.x;  // tile along N
  int by = blockIdx.y;  // tile along K
  int x = bx * 32 + threadIdx.x;
#pragma unroll
  for (int i = threadIdx.y; i < 32; i += 8)
    tile[i][threadIdx.x] = in[(size_t)(by * 32 + i) * N + x];
  __syncthreads();
  int k = by * 32 + threadIdx.x;
#pragma unroll
  for (int i = threadIdx.y; i < 32; i += 8)
    out[(size_t)(bx * 32 + i) * K + k] = __float2bfloat16(tile[threadIdx.x][i]);
}

// -------- ctx pass A: per-segment sigmoid column sums --------
__global__ void ctx_partial(const int* __restrict__ idx,
                            const float* __restrict__ Mlog,
                            float* __restrict__ segsum) {
  int b = blockIdx.x / (16 * SEG);
  int rem = blockIdx.x % (16 * SEG);
  int chunk = rem / SEG;
  int s = rem % SEG;
  int col = chunk * 256 + threadIdx.x;
  __shared__ int sidx[SEGL];
  if (threadIdx.x < SEGL)
    sidx[threadIdx.x] = idx[b * LL + s * SEGL + threadIdx.x];
  __syncthreads();
  const float* base = Mlog + col;
  float a0 = 0.f, a1 = 0.f, a2 = 0.f, a3 = 0.f;
#pragma unroll 4
  for (int t = 0; t < SEGL; t += 4) {
    float v0 = base[(size_t)sidx[t + 0] * VOCAB];
    float v1 = base[(size_t)sidx[t + 1] * VOCAB];
    float v2 = base[(size_t)sidx[t + 2] * VOCAB];
    float v3 = base[(size_t)sidx[t + 3] * VOCAB];
    a0 += 1.f / (1.f + __expf(-v0));
    a1 += 1.f / (1.f + __expf(-v1));
    a2 += 1.f / (1.f + __expf(-v2));
    a3 += 1.f / (1.f + __expf(-v3));
  }
  segsum[(size_t)blockIdx.x * 256 + threadIdx.x] = (a0 + a1) + (a2 + a3);
}

// -------- ctx pass B: replay segment with offset, write running mean --------
__global__ void ctx_final(const int* __restrict__ idx,
                          const float* __restrict__ Mlog,
                          const float* __restrict__ segsum,
                          bf16* __restrict__ ctx) {
  int b = blockIdx.x / (16 * SEG);
  int rem = blockIdx.x % (16 * SEG);
  int chunk = rem / SEG;
  int s = rem % SEG;
  int col = chunk * 256 + threadIdx.x;
  __shared__ int sidx[SEGL];
  if (threadIdx.x < SEGL)
    sidx[threadIdx.x] = idx[b * LL + s * SEGL + threadIdx.x];
  __syncthreads();
  const float* ss = segsum + (size_t)((b * 16 + chunk) * SEG) * 256 + threadIdx.x;
  float acc = 0.f;
  for (int s2 = 0; s2 < s; ++s2) acc += ss[(size_t)s2 * 256];
  const float* base = Mlog + col;
  bf16* outp = ctx + ((size_t)b * LL + (size_t)s * SEGL) * VOCAB + col;
#pragma unroll 8
  for (int t = 0; t < SEGL; ++t) {
    float v = base[(size_t)sidx[t] * VOCAB];
    acc += 1.f / (1.f + __expf(-v));
    float inv = __fdividef(1.f, (float)(s * SEGL + t + 1));
    outp[(size_t)t * VOCAB] = __float2bfloat16(acc * inv);
  }
}

// ---------------- 256x256 bf16 GEMM — barrier-minimal (2 BAR/tile) --------
// 512 thr (2x4 waves), BK=64, 128KiB LDS dbuf, chunk-XOR swizzle (0 confl),
// asm ds_read_b128. Round-7 post-mortem: 9 barriers/tile lockstepped the 2
// waves/SIMD so LDS service and MFMA serialized (5190 cyc/tile = LDS+MFMA+
// barrier). Here: per wave, each phase = {issue asm ds_reads ; issue stage ;
// lgkmcnt(0)+sched_barrier ; 16 MFMA}. Only TWO s_barrier per tile:
//   tile-top (after VMW(4)) — RAW: all 4 operand half-tiles visible
//   mid (after ph2)         — WAR: ph3/ph4 stage into regions read ph1/ph2
// Stage-WAR ledger (1 needed barrier between last-read and restage, since
// each wave's own LGKM0 precedes any later barrier):
//  ph1 stg A(t+1,h1,bo): last read t-1.ph3 -> tile-top(t)   OK
//  ph2 stg B(t+1,h0,bo): last read t-1.ph1 -> tile-top(t)   OK
//  ph3 stg A(t+2,h0,bc): last read t.ph1   -> mid(t)        OK
//  ph4 stg B(t+2,h1,bc): last read t.ph2   -> mid(t)        OK
// Waves slip up to ~half a tile -> one wave's reads overlap the sibling
// wave's MFMA cluster on the same SIMD (setprio arbitrates). bX held all
// tile (no B0 re-read): 24 reads/tile. VMW(4) steady, VMW(0) last tile.
// EPI==0: out = bf16 gelu_exact(C)   EPI==1: out = f32 C

#define BAR() asm volatile("s_barrier" ::: "memory")
#define LGKM0() asm volatile("s_waitcnt lgkmcnt(0)" ::: "memory")
#define VMW(n_) asm volatile("s_waitcnt vmcnt(" #n_ ")" ::: "memory")
#define SB0() __builtin_amdgcn_sched_barrier(0)
#define P1() __builtin_amdgcn_s_setprio(1)
#define P0() __builtin_amdgcn_s_setprio(0)

#define STG_A(t_, h_, b_)                                           \
  {                                                                 \
    const bf16* s_ = Asrc + (size_t)(h_)*128 * K + (size_t)(t_)*64; \
    bf16* d_ = sm + (b_)*32768 + (h_)*8192 + wave * 512;            \
    gload16(s_, d_);                                                \
    gload16(s_ + rowK64, d_ + 4096);                                \
  }
#define STG_B(t_, h_, b_)                                           \
  {                                                                 \
    const bf16* s_ = Bsrc + (size_t)(h_)*128 * K + (size_t)(t_)*64; \
    bf16* d_ = sm + (b_)*32768 + 16384 + (h_)*8192 + wave * 512;    \
    gload16(s_, d_);                                                \
    gload16(s_ + rowK64, d_ + 4096);                                \
  }

// one asm LDS read: 16B into a f32x4, literal byte offset
#define RD1(dst_, base_, off_)                       \
  asm volatile("ds_read_b128 %0, %1 offset:%2"       \
               : "=v"(dst_)                          \
               : "v"(base_), "i"(off_)               \
               : "memory")

// A quadrant mh_: 8 reads (4 m-frags x 2 k-chunks)
#define RD_A(b0_, b1_, mh_)                    \
  RD1(af[0][0], b0_, (mh_)*16384 + 0);         \
  RD1(af[0][1], b1_, (mh_)*16384 + 0);         \
  RD1(af[1][0], b0_, (mh_)*16384 + 2048);      \
  RD1(af[1][1], b1_, (mh_)*16384 + 2048);      \
  RD1(af[2][0], b0_, (mh_)*16384 + 4096);      \
  RD1(af[2][1], b1_, (mh_)*16384 + 4096);      \
  RD1(af[3][0], b0_, (mh_)*16384 + 6144);      \
  RD1(af[3][1], b1_, (mh_)*16384 + 6144);

// B quadrant nh_ into dst_ (bX or bY): 4 reads
#define RD_B(dst_, b0_, b1_, nh_)              \
  RD1(dst_[0][0], b0_, (nh_)*16384 + 0);       \
  RD1(dst_[0][1], b1_, (nh_)*16384 + 0);       \
  RD1(dst_[1][0], b0_, (nh_)*16384 + 2048);    \
  RD1(dst_[1][1], b1_, (nh_)*16384 + 2048);

#define MQ(mh_, nh_, B_)                                                     \
  _Pragma("unroll") for (int i_ = 0; i_ < 4; ++i_)                           \
      _Pragma("unroll") for (int j_ = 0; j_ < 2; ++j_) {                     \
    f32x4& c_ = acc[(mh_)*4 + i_][(nh_)*2 + j_];                             \
    c_ = __builtin_amdgcn_mfma_f32_16x16x32_bf16(as_bf(af[i_][0]),           \
                                                 as_bf(B_[j_][0]), c_, 0, 0, \
                                                 0);                         \
    c_ = __builtin_amdgcn_mfma_f32_16x16x32_bf16(as_bf(af[i_][1]),           \
                                                 as_bf(B_[j_][1]), c_, 0, 0, \
                                                 0);                         \
  }

#define TILE_BODY(T_, aK0_, aK1_, bK0_, bK1_, bc_)    \
  {                                                   \
    if ((T_) + 1 < NT) { VMW(4); } else { VMW(0); }   \
    BAR();                                            \
    /* ph1: rd A0,B0 ; stg A(t+1,h1,bo) ; (0,0) */    \
    RD_A(aK0_, aK1_, 0);                              \
    RD_B(bX, bK0_, bK1_, 0);                          \
    if ((T_) + 1 < NT) STG_A((T_) + 1, 1, (bc_) ^ 1); \
    LGKM0();                                          \
    SB0();                                            \
    P1(); MQ(0, 0, bX); P0();                         \
    /* ph2: rd B1 ; stg B(t+1,h0,bo) ; (0,1) */       \
    RD_B(bY, bK0_, bK1_, 1);                          \
    if ((T_) + 1 < NT) STG_B((T_) + 1, 0, (bc_) ^ 1); \
    LGKM0();                                          \
    SB0();                                            \
    P1(); MQ(0, 1, bY); P0();                         \
    BAR();                                            \
    /* ph3: rd A1 ; stg A(t+2,h0,bc) ; (1,1) */       \
    RD_A(aK0_, aK1_, 1);                              \
    if ((T_) + 2 < NT) STG_A((T_) + 2, 0, (bc_));     \
    LGKM0();                                          \
    SB0();                                            \
    P1(); MQ(1, 1, bY); P0();                         \
    /* ph4: stg B(t+2,h1,bc) ; (1,0) with held bX */  \
    if ((T_) + 2 < NT) STG_B((T_) + 2, 1, (bc_));     \
    P1(); MQ(1, 0, bX); P0();                         \
  }

template <int EPI>
__global__ __launch_bounds__(512) void gemm256(const bf16* __restrict__ A,
                                               const bf16* __restrict__ Bt,
                                               const float* __restrict__ bias,
                                               void* __restrict__ outv, int M,
                                               int N, int K) {
  __shared__ __align__(16) bf16 sm[65536];  // 128 KiB: 2 x (A 32KB | B 32KB)
  const int tid = threadIdx.x;
  const int wave = tid >> 6;
  const int lane = tid & 63;
  const int nwg = gridDim.x;
  const int bid = blockIdx.x;
  const int swz = (bid & 7) * (nwg >> 3) + (bid >> 3);  // nwg % 8 == 0
  const int gn = N >> 8;
  const int bm0 = (swz / gn) << 8;
  const int bn0 = (swz % gn) << 8;
  const int wm64 = (wave >> 2) << 6;  // wave_m * 64
  const int wn32 = (wave & 3) << 5;   // wave_n * 32
  const int rsel = lane & 15;
  const int ksel = lane >> 4;
  const int xorv = rsel & 7;

  // staging source: thread covers slots tid and tid+512 of each half-tile;
  // slot p -> row=p>>3, kc=(p&7)^(row&7)
  const int r0 = tid >> 3;
  const int kc0 = (tid & 7) ^ (r0 & 7);
  const bf16* Asrc = A + (size_t)(bm0 + r0) * K + kc0 * 8;
  const bf16* Bsrc = Bt + (size_t)(bn0 + r0) * K + kc0 * 8;
  const size_t rowK64 = (size_t)64 * K;
  const int NT = K >> 6;

  // 32-bit LDS byte bases for asm ds_read (chunk-XOR folded in)
  const unsigned smbase =
      (unsigned)(unsigned long long)(__attribute__((address_space(3)))
                                     bf16*)sm;
  const unsigned kT0 = (unsigned)((ksel ^ xorv) << 4);
  const unsigned kT1 = (unsigned)(((ksel + 4) ^ xorv) << 4);
  const unsigned aRow = (unsigned)((wm64 + rsel) * 128);
  const unsigned bRow = (unsigned)((wn32 + rsel) * 128);
  const unsigned a00 = smbase + aRow + kT0;
  const unsigned a10 = smbase + aRow + kT1;
  const unsigned b00 = smbase + 32768u + bRow + kT0;
  const unsigned b10 = smbase + 32768u + bRow + kT1;
  const unsigned a01 = a00 + 65536u, a11 = a10 + 65536u;
  const unsigned b01 = b00 + 65536u, b11 = b10 + 65536u;

  f32x4 acc[8][4];
#pragma unroll
  for (int i = 0; i < 8; ++i)
#pragma unroll
    for (int j = 0; j < 4; ++j) acc[i][j] = (f32x4){0.f, 0.f, 0.f, 0.f};

  f32x4 af[4][2], bX[2][2], bY[2][2];

  // prologue: tile0 all 4 halves, then steady-state in-flight pair
  // {A(1,h0), B(1,h1)} (matches t-1.ph3/ph4 of the steady FIFO)
  STG_A(0, 0, 0);
  STG_B(0, 0, 0);
  STG_B(0, 1, 0);
  STG_A(0, 1, 0);
  STG_A(1, 0, 1);
  STG_B(1, 1, 1);

  for (int t = 0; t < NT; t += 2) {
    TILE_BODY(t, a00, a10, b00, b10, 0);
    TILE_BODY(t + 1, a01, a11, b01, b11, 1);
  }

  // epilogue; C/D layout: col = lane&15, row = (lane>>4)*4 + reg
  const int cl = lane & 15;
  const int rg = lane >> 4;
#pragma unroll
  for (int m = 0; m < 8; ++m) {
    int grow = bm0 + ((m >> 2) << 7) + wm64 + ((m & 3) << 4) + rg * 4;
#pragma unroll
    for (int n = 0; n < 4; ++n) {
      int col = bn0 + ((n >> 1) << 7) + wn32 + ((n & 1) << 4) + cl;
      float bv = bias[col];
#pragma unroll
      for (int r = 0; r < 4; ++r) {
        size_t o = (size_t)(grow + r) * N + col;
        float v = acc[m][n][r] + bv;
        if (EPI == 0) {
          float g = 0.5f * v * (1.f + erff(v * 0.70710678118654752f));
          ((bf16*)outv)[o] = __float2bfloat16(g);
        } else {
          ((float*)outv)[o] = v;
        }
      }
    }
  }
}

extern "C" void kernel_launch(void* const* d_in, const int* in_sizes, int n_in,
                              void* d_out, int out_size, void* d_ws,
                              size_t ws_size, hipStream_t stream) {
  const int* idx = (const int*)d_in[0];       // [B,L]
  const float* Mlog = (const float*)d_in[1];  // [V,V]
  const float* W1 = (const float*)d_in[2];    // [V,2V]
  const float* b1 = (const float*)d_in[3];    // [2V]
  const float* W2 = (const float*)d_in[4];    // [2V,V]
  const float* b2 = (const float*)d_in[5];    // [V]
  float* out = (float*)d_out;                 // [B,L,V] f32

  char* ws = (char*)d_ws;
  const size_t MB64 = 64ull << 20;
  bf16* ctx = (bf16*)ws;             // 64 MiB  [8192][4096] (dead after GEMM1)
  bf16* W2t = (bf16*)ws;             // aliases ctx: [4096][8192]
  bf16* W1t = (bf16*)(ws + MB64);    // 64 MiB  [8192][4096]
  bf16* h = (bf16*)(ws + 2 * MB64);  // 128 MiB [8192][8192]
  float* segsum = (float*)h;         // 1 MiB, dead before GEMM1 writes h
  (void)ws_size;

  dim3 tb(32, 8);
  // W1^T cast
  transpose_f32_bf16<<<dim3(8192 / 32, 4096 / 32), tb, 0, stream>>>(W1, W1t,
                                                                    4096, 8192);
  // ctx = causal-mean(sigmoid(M)[idx]), segment-parallel two-pass
  ctx_partial<<<BB * 16 * SEG, 256, 0, stream>>>(idx, Mlog, segsum);
  ctx_final<<<BB * 16 * SEG, 256, 0, stream>>>(idx, Mlog, segsum, ctx);
  // h = gelu(ctx @ W1 + b1)  -> bf16
  gemm256<0><<<(8192 / 256) * (8192 / 256), 512, 0, stream>>>(
      ctx, W1t, b1, h, 8192, 8192, 4096);
  // W2^T cast (reuses ctx space)
  transpose_f32_bf16<<<dim3(4096 / 32, 8192 / 32), tb, 0, stream>>>(W2, W2t,
                                                                    8192, 4096);
  // out = h @ W2 + b2  -> f32
  gemm256<1><<<(8192 / 256) * (4096 / 256), 512, 0, stream>>>(
      h, W2t, b2, out, 8192, 4096, 8192);
}